// Round 1
// baseline (140.641 us; speedup 1.0000x reference)
//
#include <hip/hip_runtime.h>
#include <hip/hip_bf16.h>

// CapsuleLayer on MI355X — R5: barrier-free MFMA main loop (B direct from L2,
// no Bs LDS staging, zero per-kk barriers) + vectorized fused pre/reorder.
// b stays 0 (faithful torch bug) => one dense conv 64ci->128co, 5x5, pad 2;
// v = squash_z1(p/(8*cnt)); out [N, t1, z1, H, W].

#define CO 128

typedef __attribute__((ext_vector_type(8))) short bf16x8;
typedef __attribute__((ext_vector_type(4))) float f32x4;

// ---- fused prep:
//   blocks [0,800):   W fp32 [t0][co][z0][5][5] -> Wr2 bf16 [kk][co][ci]
//   blocks [800,1824): u [n][ci][h][w] fp32 -> ut [n][h][w][ci] bf16
// (independent outputs; fused to overlap and save one launch gap)
__global__ __launch_bounds__(256) void k_prep(const float* __restrict__ u,
                                              const float* __restrict__ Wsrc,
                                              ushort* __restrict__ ut,
                                              ushort* __restrict__ Wr2) {
    __shared__ float lt[64][65];
    int b = blockIdx.x;
    int t = threadIdx.x;
    if (b < 800) {
        int idx = b * 256 + t;                  // (kk*128+co)*64+ci
        int ci = idx & 63;
        int r  = idx >> 6;
        int co = r & 127;
        int kk = r >> 7;
        int t0 = ci >> 4, z0 = ci & 15;
        __hip_bfloat16 bb = __float2bfloat16(Wsrc[((t0 * CO + co) * 16 + z0) * 25 + kk]);
        Wr2[idx] = *(ushort*)&bb;
        return;
    }
    b -= 800;                                   // (n*128 + h)*2 + wchunk
    int wc = b & 1; int nh = b >> 1; int h = nh & 127; int n = nh >> 7;
    int w0 = wc * 64;
    // load: float4 per thread, 4 passes. lanes: ci = p*16 + (t>>4), w = (t&15)*4
    // LDS write bank = (w + j + ci) % 32 -> 2-way (free, m136)
    int ciL = t >> 4;
    int wl  = (t & 15) * 4;
    const float* up = u + (size_t)n * (64 * 128 * 128) + h * 128 + w0;
#pragma unroll
    for (int p = 0; p < 4; ++p) {
        int ci = p * 16 + ciL;
        float4 v = *(const float4*)(up + (size_t)ci * 16384 + wl);
        lt[wl + 0][ci] = v.x;
        lt[wl + 1][ci] = v.y;
        lt[wl + 2][ci] = v.z;
        lt[wl + 3][ci] = v.w;
    }
    __syncthreads();
    // store: bf16x8 (16B) per thread, 2 passes. item -> c8 = item&7, w2 = item>>3
    // LDS read bank = (w2 + 8*(c8&3) + j) % 32 -> 2-way (free)
    ushort* op = ut + (((size_t)(n * 128 + h)) * 128 + w0) * 64;
#pragma unroll
    for (int p = 0; p < 2; ++p) {
        int item = p * 256 + t;
        int c8 = item & 7, w2 = item >> 3;
        bf16x8 vv;
#pragma unroll
        for (int j = 0; j < 8; ++j) {
            __hip_bfloat16 bb = __float2bfloat16(lt[w2][c8 * 8 + j]);
            vv[j] = *(ushort*)&bb;
        }
        *(bf16x8*)(op + (size_t)w2 * 64 + c8 * 8) = vv;
    }
}

// ---- main: grid 512 = 4(n) x 16(by: 8 rows) x 8(bx: 16 cols), 256 thr = 4 waves
// wave: wm4 = (wid>>1)*4 -> image rows [h0+wm4, +4); wn64 = (wid&1)*64 -> co.
// As row stride 80 ushorts (160 B): HW-verified conflict-free frag pattern (R4).
// B fragments loaded per-kk DIRECTLY from Wr2 (L2-resident 400 KB, identical
// across all blocks) with prefetch depth 1 -> main loop has NO barriers.
__global__ __launch_bounds__(256) void k_caps(const ushort* __restrict__ ut,
                                              const ushort* __restrict__ Wr2,
                                              float* __restrict__ out) {
    __shared__ ushort As[240 * 80];   // [p = rr*20+cc][ci pad] 38400 B

    int tid = threadIdx.x;
    int bid = blockIdx.x;
    int bx = bid & 7, by = (bid >> 3) & 15, n = bid >> 7;
    int h0 = by * 8, w0 = bx * 16;

    int lane = tid & 63, wid = tid >> 6;
    int wm4  = (wid >> 1) * 4;
    int wn64 = (wid & 1) * 64;
    int q = lane >> 4, m16 = lane & 15;

    // per-lane B base: element (co = wn64+ni*16+m16, ci = ks*32+q*8+j) of Wr2[kk]
    const ushort* bp = Wr2 + (size_t)(wn64 + m16) * 64 + q * 8;

    // issue kk=0 B loads early — they fly under the As staging
    bf16x8 bc[2][4];
#pragma unroll
    for (int ks = 0; ks < 2; ++ks)
#pragma unroll
        for (int ni = 0; ni < 4; ++ni)
            bc[ks][ni] = *(const bf16x8*)(bp + ni * 1024 + ks * 32);

    // stage A tile (pad-2 halo, zero OOB): 240 pixels x 8 chunks of 8 ci
    for (int i = tid; i < 1920; i += 256) {
        int p = i >> 3, c = i & 7;
        int rr = p / 20, cc = p - rr * 20;
        int hh = h0 + rr - 2, ww = w0 + cc - 2;
        bf16x8 v = {};
        if ((unsigned)hh < 128u && (unsigned)ww < 128u)
            v = *(const bf16x8*)(ut + (((size_t)(n * 128 + hh)) * 128 + ww) * 64 + c * 8);
        *(bf16x8*)&As[p * 80 + c * 8] = v;
    }
    __syncthreads();                  // the ONLY barrier: As is read-only below

    int aBase = (wm4 * 20 + m16) * 80 + q * 8;

    f32x4 acc[4][4] = {};

    for (int kh = 0; kh < 5; ++kh) {          // dynamic outer (reg pressure)
#pragma unroll
        for (int kw = 0; kw < 5; ++kw) {
            // prefetch next kk's B frags (runtime cond only in kw==4 body)
            bf16x8 bn[2][4];
            bool pf = (kw < 4) || (kh < 4);
            if (pf) {
                const ushort* np = bp + (size_t)(kh * 5 + kw + 1) * 8192;
#pragma unroll
                for (int ks = 0; ks < 2; ++ks)
#pragma unroll
                    for (int ni = 0; ni < 4; ++ni)
                        bn[ks][ni] = *(const bf16x8*)(np + ni * 1024 + ks * 32);
            }
#pragma unroll
            for (int ks = 0; ks < 2; ++ks) {
                bf16x8 a[4];
#pragma unroll
                for (int mi = 0; mi < 4; ++mi)
                    a[mi] = *(const bf16x8*)&As[aBase + ((mi + kh) * 20 + kw) * 80 + ks * 32];
#pragma unroll
                for (int mi = 0; mi < 4; ++mi)
#pragma unroll
                    for (int ni = 0; ni < 4; ++ni)
                        acc[mi][ni] = __builtin_amdgcn_mfma_f32_16x16x32_bf16(
                            a[mi], bc[ks][ni], acc[mi][ni], 0, 0, 0);
            }
            if (pf) {
#pragma unroll
                for (int ks = 0; ks < 2; ++ks)
#pragma unroll
                    for (int ni = 0; ni < 4; ++ni)
                        bc[ks][ni] = bn[ks][ni];
            }
        }
    }

    // epilogue (R3-proven): scale 1/(8*cnt), squash over z1 (m16 lanes), store
    // D layout: row(m = image col) = q*4+reg, col(n = co) = m16
#pragma unroll
    for (int mi = 0; mi < 4; ++mi) {
        int h = h0 + wm4 + mi;
        int hlo = h - 2; if (hlo < 0) hlo = 0;
        int hhi = h + 2; if (hhi > 127) hhi = 127;
        float cnth = (float)(hhi - hlo + 1);
#pragma unroll
        for (int ni = 0; ni < 4; ++ni) {
            f32x4 cv = acc[mi][ni];
            float ov[4];
#pragma unroll
            for (int reg = 0; reg < 4; ++reg) {
                int w = w0 + q * 4 + reg;
                int wlo = w - 2; if (wlo < 0) wlo = 0;
                int whi = w + 2; if (whi > 127) whi = 127;
                float s = 1.f / (8.f * cnth * (float)(whi - wlo + 1));
                float pv = cv[reg] * s;
                float n2 = pv * pv;
                n2 += __shfl_xor(n2, 1);
                n2 += __shfl_xor(n2, 2);
                n2 += __shfl_xor(n2, 4);
                n2 += __shfl_xor(n2, 8);
                float fac = n2 / ((1.f + n2) * sqrtf(n2 + 1e-9f));
                ov[reg] = pv * fac;
            }
            int co = wn64 + ni * 16 + m16;
            *(float4*)(out + (((size_t)(n * CO + co)) << 14) + h * 128 + w0 + q * 4) =
                make_float4(ov[0], ov[1], ov[2], ov[3]);
        }
    }
}

extern "C" void kernel_launch(void* const* d_in, const int* in_sizes, int n_in,
                              void* d_out, int out_size, void* d_ws, size_t ws_size,
                              hipStream_t stream) {
    const float* u    = (const float*)d_in[0];
    const float* Wsrc = (const float*)d_in[1];
    float* out = (float*)d_out;
    ushort* Wr2 = (ushort*)d_ws;                       // 409600 B
    ushort* ut  = (ushort*)((char*)d_ws + 409600);     // 8388608 B

    k_prep<<<1824, 256, 0, stream>>>(u, Wsrc, ut, Wr2);
    k_caps<<<512, 256, 0, stream>>>(ut, Wr2, out);
}

// Round 2
// 107.502 us; speedup vs baseline: 1.3083x; 1.3083x over previous
//
#include <hip/hip_runtime.h>
#include <hip/hip_bf16.h>

// CapsuleLayer on MI355X — R6: LDS-staged B restored (R5 post-mortem: direct
// L2 B-frag loads are TA-transaction-bound, 8x line touches). New structure:
// double-buffered Bs with ONE barrier per kk, staged via global_load_lds
// width-16 into a dense [co][64] layout with XOR chunk-swizzle (chunk^=co&7)
// pre-baked into Wr2 (rule 21: pre-swizzled source + swizzled read).
// b stays 0 (faithful torch bug) => one dense conv 64ci->128co, 5x5, pad 2;
// v = squash_z1(p/(8*cnt)); out [N, t1, z1, H, W].

#define CO 128

typedef __attribute__((ext_vector_type(8))) short bf16x8;
typedef __attribute__((ext_vector_type(4))) float f32x4;

__device__ __forceinline__ void glds16(const void* g, void* l) {
    __builtin_amdgcn_global_load_lds((const __attribute__((address_space(1))) void*)g,
                                     (__attribute__((address_space(3))) void*)l, 16, 0, 0);
}

// ---- fused prep:
//   blocks [0,800):   W fp32 [t0][co][z0][5][5] -> Wr2 bf16 [kk][co][chunk^ (co&7)][8]
//   blocks [800,1824): u [n][ci][h][w] fp32 -> ut [n][h][w][ci] bf16
__global__ __launch_bounds__(256) void k_prep(const float* __restrict__ u,
                                              const float* __restrict__ Wsrc,
                                              ushort* __restrict__ ut,
                                              ushort* __restrict__ Wr2) {
    __shared__ float lt[64][65];
    int b = blockIdx.x;
    int t = threadIdx.x;
    if (b < 800) {
        int idx = b * 256 + t;                  // flat over (kk*128+co)*64+ci
        int ci = idx & 63;
        int r  = idx >> 6;
        int co = r & 127;
        int kk = r >> 7;
        int t0 = ci >> 4, z0 = ci & 15;
        __hip_bfloat16 bb = __float2bfloat16(Wsrc[((t0 * CO + co) * 16 + z0) * 25 + kk]);
        int chunk = (ci >> 3) ^ (co & 7);       // XOR swizzle baked into Wr2
        Wr2[((kk * CO + co) << 6) + (chunk << 3) + (ci & 7)] = *(ushort*)&bb;
        return;
    }
    b -= 800;                                   // (n*128 + h)*2 + wchunk
    int wc = b & 1; int nh = b >> 1; int h = nh & 127; int n = nh >> 7;
    int w0 = wc * 64;
    // load: float4 per thread, 4 passes. lanes: ci = p*16 + (t>>4), w = (t&15)*4
    int ciL = t >> 4;
    int wl  = (t & 15) * 4;
    const float* up = u + (size_t)n * (64 * 128 * 128) + h * 128 + w0;
#pragma unroll
    for (int p = 0; p < 4; ++p) {
        int ci = p * 16 + ciL;
        float4 v = *(const float4*)(up + (size_t)ci * 16384 + wl);
        lt[wl + 0][ci] = v.x;
        lt[wl + 1][ci] = v.y;
        lt[wl + 2][ci] = v.z;
        lt[wl + 3][ci] = v.w;
    }
    __syncthreads();
    // store: bf16x8 (16B) per thread, 2 passes (1 KB contiguous per wave)
    ushort* op = ut + (((size_t)(n * 128 + h)) * 128 + w0) * 64;
#pragma unroll
    for (int p = 0; p < 2; ++p) {
        int item = p * 256 + t;
        int c8 = item & 7, w2 = item >> 3;
        bf16x8 vv;
#pragma unroll
        for (int j = 0; j < 8; ++j) {
            __hip_bfloat16 bb = __float2bfloat16(lt[w2][c8 * 8 + j]);
            vv[j] = *(ushort*)&bb;
        }
        *(bf16x8*)(op + (size_t)w2 * 64 + c8 * 8) = vv;
    }
}

// ---- main: grid 512 = 4(n) x 16(by: 8 rows) x 8(bx: 16 cols), 256 thr = 4 waves
// wave: wm4 = (wid>>1)*4 -> image rows [h0+wm4, +4); wn64 = (wid&1)*64 -> co.
// As row stride 80 ushorts: HW-verified conflict-free frag pattern (R4).
// Bs: double-buffered dense [co][64] staged by global_load_lds (linear dest);
// frag read applies chunk^(co&7) -> dword banks 4*((ks*4+q)^(m16&7)): 2-way, free.
// ONE __syncthreads per kk (drain doubles as the glds wait).
__global__ __launch_bounds__(256) void k_caps(const ushort* __restrict__ ut,
                                              const ushort* __restrict__ Wr2,
                                              float* __restrict__ out) {
    __shared__ ushort As[240 * 80];   // [p = rr*20+cc][ci pad] 38400 B
    __shared__ ushort Bs[2][128 * 64]; // dbuf, dense swizzled      32768 B

    int tid = threadIdx.x;
    int bid = blockIdx.x;
    int bx = bid & 7, by = (bid >> 3) & 15, n = bid >> 7;
    int h0 = by * 8, w0 = bx * 16;

    int lane = tid & 63, wid = tid >> 6;
    int wm4  = (wid >> 1) * 4;
    int wn64 = (wid & 1) * 64;
    int q = lane >> 4, m16 = lane & 15;
    int m7 = m16 & 7;

    // prologue: issue kk=0 B staging (flies under the As staging)
#pragma unroll
    for (int j = 0; j < 4; ++j) {
        int i = (j * 256 + wid * 64) * 8;      // wave-uniform lds base, lane adds *16B
        glds16(Wr2 + (size_t)(i + lane * 8), &Bs[0][i]);
    }

    // stage A tile (pad-2 halo, zero OOB): 240 pixels x 8 chunks of 8 ci
    for (int i = tid; i < 1920; i += 256) {
        int p = i >> 3, c = i & 7;
        int rr = p / 20, cc = p - rr * 20;
        int hh = h0 + rr - 2, ww = w0 + cc - 2;
        bf16x8 v = {};
        if ((unsigned)hh < 128u && (unsigned)ww < 128u)
            v = *(const bf16x8*)(ut + (((size_t)(n * 128 + hh)) * 128 + ww) * 64 + c * 8);
        *(bf16x8*)&As[p * 80 + c * 8] = v;
    }
    __syncthreads();                  // As ready + Bs[0] landed

    int aBase = (wm4 * 20 + m16) * 80 + q * 8;
    int bRow  = (wn64 + m16) << 6;    // dense row base (ushorts)

    f32x4 acc[4][4] = {};

#pragma unroll
    for (int kk = 0; kk < 25; ++kk) {
        const int kh = kk / 5, kw = kk % 5;
        const int cur = kk & 1;
        if (kk < 24) {                 // stage next kk into other buffer (no reader conflict)
#pragma unroll
            for (int j = 0; j < 4; ++j) {
                int i = (j * 256 + wid * 64) * 8;
                glds16(Wr2 + (size_t)(kk + 1) * 8192 + i + lane * 8, &Bs[cur ^ 1][i]);
            }
        }
#pragma unroll
        for (int ks = 0; ks < 2; ++ks) {
            int sw = ((ks * 4 + q) ^ m7) << 3;
            bf16x8 a[4], bb[4];
#pragma unroll
            for (int mi = 0; mi < 4; ++mi)
                a[mi] = *(const bf16x8*)&As[aBase + ((mi + kh) * 20 + kw) * 80 + ks * 32];
#pragma unroll
            for (int ni = 0; ni < 4; ++ni)
                bb[ni] = *(const bf16x8*)&Bs[cur][bRow + ni * 1024 + sw];
#pragma unroll
            for (int mi = 0; mi < 4; ++mi)
#pragma unroll
                for (int ni = 0; ni < 4; ++ni)
                    acc[mi][ni] = __builtin_amdgcn_mfma_f32_16x16x32_bf16(
                        a[mi], bb[ni], acc[mi][ni], 0, 0, 0);
        }
        if (kk < 24) __syncthreads();  // drains glds (vmcnt) + guards buffer swap
    }

    // epilogue (R3-proven): scale 1/(8*cnt), squash over z1 (m16 lanes), store
    // D layout: row(m = image col) = q*4+reg, col(n = co) = m16
#pragma unroll
    for (int mi = 0; mi < 4; ++mi) {
        int h = h0 + wm4 + mi;
        int hlo = h - 2; if (hlo < 0) hlo = 0;
        int hhi = h + 2; if (hhi > 127) hhi = 127;
        float cnth = (float)(hhi - hlo + 1);
#pragma unroll
        for (int ni = 0; ni < 4; ++ni) {
            f32x4 cv = acc[mi][ni];
            float ov[4];
#pragma unroll
            for (int reg = 0; reg < 4; ++reg) {
                int w = w0 + q * 4 + reg;
                int wlo = w - 2; if (wlo < 0) wlo = 0;
                int whi = w + 2; if (whi > 127) whi = 127;
                float s = 1.f / (8.f * cnth * (float)(whi - wlo + 1));
                float pv = cv[reg] * s;
                float n2 = pv * pv;
                n2 += __shfl_xor(n2, 1);
                n2 += __shfl_xor(n2, 2);
                n2 += __shfl_xor(n2, 4);
                n2 += __shfl_xor(n2, 8);
                float fac = n2 / ((1.f + n2) * sqrtf(n2 + 1e-9f));
                ov[reg] = pv * fac;
            }
            int co = wn64 + ni * 16 + m16;
            *(float4*)(out + (((size_t)(n * CO + co)) << 14) + h * 128 + w0 + q * 4) =
                make_float4(ov[0], ov[1], ov[2], ov[3]);
        }
    }
}

extern "C" void kernel_launch(void* const* d_in, const int* in_sizes, int n_in,
                              void* d_out, int out_size, void* d_ws, size_t ws_size,
                              hipStream_t stream) {
    const float* u    = (const float*)d_in[0];
    const float* Wsrc = (const float*)d_in[1];
    float* out = (float*)d_out;
    ushort* Wr2 = (ushort*)d_ws;                       // 409600 B
    ushort* ut  = (ushort*)((char*)d_ws + 409600);     // 8388608 B

    k_prep<<<1824, 256, 0, stream>>>(u, Wsrc, ut, Wr2);
    k_caps<<<512, 256, 0, stream>>>(ut, Wr2, out);
}

// Round 3
// 107.219 us; speedup vs baseline: 1.3117x; 1.0026x over previous
//
#include <hip/hip_runtime.h>
#include <hip/hip_bf16.h>

// CapsuleLayer on MI355X — R7: (a) k_prep transpose eliminated — k_caps stages
// As directly from fp32 u (gather 8 ci-strided scalars/px, cvt, ds_write_b128);
// (b) T3/T4: triple-buffered Bs via global_load_lds with COUNTED s_waitcnt
// vmcnt(4) + raw s_barrier (prefetch depth 2, never drained mid-loop);
// (c) As dense [240][64] + T2 XOR chunk-swizzle (chunk^=p&7) to fit 3x16KB Bs
// in 80KB/block (2 blocks/CU); (d) T5 setprio around MFMA cluster.
// b stays 0 (faithful torch bug) => one dense conv 64ci->128co, 5x5, pad 2;
// v = squash_z1(p/(8*cnt)); out [N, t1, z1, H, W].

#define CO 128

typedef __attribute__((ext_vector_type(8))) short bf16x8;
typedef __attribute__((ext_vector_type(4))) float f32x4;

__device__ __forceinline__ void glds16(const void* g, void* l) {
    __builtin_amdgcn_global_load_lds((const __attribute__((address_space(1))) void*)g,
                                     (__attribute__((address_space(3))) void*)l, 16, 0, 0);
}

// ---- W fp32 [t0][co][z0][5][5] -> Wr2 bf16 [kk][co][chunk^(co&7)][8]
__global__ __launch_bounds__(256) void k_reorder(const float* __restrict__ Wsrc,
                                                 ushort* __restrict__ Wr2) {
    int idx = blockIdx.x * 256 + threadIdx.x;   // 800 blocks = 25*128*64 exact
    int ci = idx & 63;
    int r  = idx >> 6;
    int co = r & 127;
    int kk = r >> 7;
    int t0 = ci >> 4, z0 = ci & 15;
    __hip_bfloat16 bb = __float2bfloat16(Wsrc[((t0 * CO + co) * 16 + z0) * 25 + kk]);
    int chunk = (ci >> 3) ^ (co & 7);           // XOR swizzle baked into Wr2
    Wr2[((kk * CO + co) << 6) + (chunk << 3) + (ci & 7)] = *(ushort*)&bb;
}

// ---- main: grid 512 = 4(n) x 16(by: 8 rows) x 8(bx: 16 cols), 256 thr = 4 waves
// wave: wm4 = (wid>>1)*4 -> image rows [h0+wm4, +4); wn64 = (wid&1)*64 -> co.
// As dense [p][64], chunk XOR p&7 (write+read involution): frag reads cover
// 8 bank-quads x 8 lanes = b128 floor. Bs: 3 buffers, counted vmcnt(4),
// raw s_barrier -> kk+2's glds stay in flight across the barrier.
__global__ __launch_bounds__(256) void k_caps(const float* __restrict__ u,
                                              const ushort* __restrict__ Wr2,
                                              float* __restrict__ out) {
    __shared__ ushort As[240 * 64];      // 30720 B, dense swizzled
    __shared__ ushort Bs[3][128 * 64];   // 49152 B, triple-buffered

    int tid = threadIdx.x;
    int bid = blockIdx.x;
    int bx = bid & 7, by = (bid >> 3) & 15, n = bid >> 7;
    int h0 = by * 8, w0 = bx * 16;

    int lane = tid & 63, wid = tid >> 6;
    int wm4  = (wid >> 1) * 4;
    int wn64 = (wid & 1) * 64;
    int q = lane >> 4, m16 = lane & 15;
    int m7 = m16 & 7;

    auto stageB = [&](int kk2, int buf) {
#pragma unroll
        for (int j = 0; j < 4; ++j) {
            int i = (j * 256 + wid * 64) * 8;   // wave-uniform LDS base; lane adds 16B
            glds16(Wr2 + (size_t)kk2 * 8192 + i + lane * 8, &Bs[buf][i]);
        }
    };

    // B0 prefetch first — flies under the A staging
    stageB(0, 0);

    // ---- A staging directly from u: thread = pixel p (<240), 8 octet phases,
    // 8 ci-strided scalar loads (coalesced across lanes along w), cvt+pack.
    {
        int p = tid;
        int rr = p / 20;
        int cc = p - rr * 20;
        int hh = h0 + rr - 2, ww = w0 + cc - 2;
        bool inb = (p < 240) & ((unsigned)hh < 128u) & ((unsigned)ww < 128u);
        const float* up = u + (size_t)n * (64 * 128 * 128) + (size_t)hh * 128 + ww;
        int key = (p & 7) << 3;
#pragma unroll
        for (int c8 = 0; c8 < 8; ++c8) {
            bf16x8 vv = {};
            if (inb) {
#pragma unroll
                for (int j = 0; j < 8; ++j) {
                    __hip_bfloat16 bb =
                        __float2bfloat16(up[(size_t)(c8 * 8 + j) * 16384]);
                    vv[j] = *(ushort*)&bb;
                }
            }
            if (p < 240)
                *(bf16x8*)&As[(p << 6) + ((c8 << 3) ^ key)] = vv;
        }
    }
    __syncthreads();                 // full drain: As + B0 landed
    stageB(1, 1);                    // B1 in flight, depth 2 from here on

    int aP0  = wm4 * 20 + m16;       // lane pixel base
    int bRow = (wn64 + m16) << 6;
    int bsw0 = (q ^ m7) << 3;        // ks=0 B chunk swizzle (lane-const)
    int bsw1 = ((4 + q) ^ m7) << 3;  // ks=1

    f32x4 acc[4][4] = {};

#pragma unroll
    for (int kk = 0; kk < 25; ++kk) {
        const int kh = kk / 5, kw = kk % 5;
        const int cur = kk % 3;
        if (kk < 23) stageB(kk + 2, (kk + 2) % 3);
        __builtin_amdgcn_s_setprio(1);
#pragma unroll
        for (int ks = 0; ks < 2; ++ks) {
            int bsw = ks ? bsw1 : bsw0;
            bf16x8 a[4], bb[4];
#pragma unroll
            for (int mi = 0; mi < 4; ++mi) {
                int p = aP0 + (mi + kh) * 20 + kw;
                int asw = (((ks << 2) + q) ^ (p & 7)) << 3;
                a[mi] = *(const bf16x8*)&As[(p << 6) + asw];
            }
#pragma unroll
            for (int ni = 0; ni < 4; ++ni)
                bb[ni] = *(const bf16x8*)&Bs[cur][bRow + ni * 1024 + bsw];
#pragma unroll
            for (int mi = 0; mi < 4; ++mi)
#pragma unroll
                for (int ni = 0; ni < 4; ++ni)
                    acc[mi][ni] = __builtin_amdgcn_mfma_f32_16x16x32_bf16(
                        a[mi], bb[ni], acc[mi][ni], 0, 0, 0);
        }
        __builtin_amdgcn_s_setprio(0);
        if (kk < 24) {
            // counted wait: kk+1's 4 glds retired, kk+2's 4 stay IN FLIGHT
            if (kk < 23) asm volatile("s_waitcnt vmcnt(4)" ::: "memory");
            else         asm volatile("s_waitcnt vmcnt(0)" ::: "memory");
            asm volatile("s_barrier" ::: "memory");
        }
    }

    // epilogue (R3-proven): scale 1/(8*cnt), squash over z1 (m16 lanes), store
    // D layout: row(m = image col) = q*4+reg, col(n = co) = m16
#pragma unroll
    for (int mi = 0; mi < 4; ++mi) {
        int h = h0 + wm4 + mi;
        int hlo = h - 2; if (hlo < 0) hlo = 0;
        int hhi = h + 2; if (hhi > 127) hhi = 127;
        float cnth = (float)(hhi - hlo + 1);
#pragma unroll
        for (int ni = 0; ni < 4; ++ni) {
            f32x4 cv = acc[mi][ni];
            float ov[4];
#pragma unroll
            for (int reg = 0; reg < 4; ++reg) {
                int w = w0 + q * 4 + reg;
                int wlo = w - 2; if (wlo < 0) wlo = 0;
                int whi = w + 2; if (whi > 127) whi = 127;
                float s = 1.f / (8.f * cnth * (float)(whi - wlo + 1));
                float pv = cv[reg] * s;
                float n2 = pv * pv;
                n2 += __shfl_xor(n2, 1);
                n2 += __shfl_xor(n2, 2);
                n2 += __shfl_xor(n2, 4);
                n2 += __shfl_xor(n2, 8);
                float fac = n2 / ((1.f + n2) * sqrtf(n2 + 1e-9f));
                ov[reg] = pv * fac;
            }
            int co = wn64 + ni * 16 + m16;
            *(float4*)(out + (((size_t)(n * CO + co)) << 14) + h * 128 + w0 + q * 4) =
                make_float4(ov[0], ov[1], ov[2], ov[3]);
        }
    }
}

extern "C" void kernel_launch(void* const* d_in, const int* in_sizes, int n_in,
                              void* d_out, int out_size, void* d_ws, size_t ws_size,
                              hipStream_t stream) {
    const float* u    = (const float*)d_in[0];
    const float* Wsrc = (const float*)d_in[1];
    float* out = (float*)d_out;
    ushort* Wr2 = (ushort*)d_ws;                       // 409600 B

    k_reorder<<<800, 256, 0, stream>>>(Wsrc, Wr2);
    k_caps<<<512, 256, 0, stream>>>(u, Wr2, out);
}